// Round 10
// baseline (320.947 us; speedup 1.0000x reference)
//
#include <hip/hip_runtime.h>
#include <hip/hip_fp16.h>

#define NODES 50000
#define EDGES 800000
#define DIM 128
#define EPS_BN 1e-5f
#define SCAN_B 1024
#define SCAN_NB ((NODES + SCAN_B - 1) / SCAN_B)   // 49
#define GEMM_NB ((NODES + 63) / 64)               // 782
#define NCH 64                                    // edge chunks
#define CHE (EDGES / NCH)                         // 12500 edges/chunk
#define NR 4                                      // node ranges
#define RNG (NODES / NR)                          // 12500 nodes/range
#define PRE_NB ((NODES * 16) / 256)               // 3125 prescale blocks
#define EDGE_NB ((EDGES + 255) / 256)             // 3125 edge-parallel blocks
#define PULL_NB (NODES)                           // 50000 blocks: (node x quarter) waves

typedef _Float16 half8 __attribute__((ext_vector_type(8)));
typedef _Float16 half4 __attribute__((ext_vector_type(4)));
typedef float floatx4 __attribute__((ext_vector_type(4)));

union H8 { half8 v; __half2 h2[4]; };
union H4 { half4 v; __half2 h2[2]; };

// hs layout is COLUMN-QUARTERED: hs[q][node][32] fp16 (quarter = 3.2 MB, fits 4 MiB
// per-XCD L2). Quarter q is gathered only by blocks with (blockIdx&7)>>1 == q, i.e.
// XCD pair {2q,2q+1} under the standard round-robin block->XCD mapping.

// ---------------- pass 1: partial LDS histograms; dst pass also emits local rank ----
__global__ __launch_bounds__(256) void hist_part_kernel(const int* __restrict__ src,
                                                        const int* __restrict__ dst,
                                                        unsigned short* __restrict__ Psrc,
                                                        unsigned short* __restrict__ Pdst,
                                                        unsigned short* __restrict__ rlocal) {
    __shared__ int h[RNG];   // 50 KB
    int chunk = blockIdx.x & (NCH - 1);
    int range = blockIdx.x >> 6;
    const int* arr = blockIdx.y ? dst : src;
    unsigned short* P = blockIdx.y ? Pdst : Psrc;
    int base = range * RNG;
    for (int i = threadIdx.x; i < RNG; i += 256) h[i] = 0;
    __syncthreads();
    int e0 = chunk * CHE;
    for (int e = e0 + threadIdx.x; e < e0 + CHE; e += 256) {
        unsigned r = (unsigned)(arr[e] - base);
        if (r < (unsigned)RNG) {
            int local = atomicAdd(&h[r], 1);
            if (blockIdx.y) rlocal[e] = (unsigned short)local;   // rank within (chunk, d)
        }
    }
    __syncthreads();
    for (int i = threadIdx.x; i < RNG; i += 256)
        P[(size_t)chunk * NODES + base + i] = (unsigned short)h[i];
}

// ---------------- pass 2: degrees + per-chunk scan bases ----------------
__global__ __launch_bounds__(256) void combine_kernel(const unsigned short* __restrict__ Psrc,
                                                      unsigned short* __restrict__ Pdst,
                                                      int* __restrict__ cnt_in,
                                                      float* __restrict__ dn_out,
                                                      float* __restrict__ sdeg,
                                                      float* __restrict__ dn_in) {
    int v = blockIdx.x * 256 + threadIdx.x;
    if (v >= NODES) return;
    int s = 0;
    #pragma unroll 8
    for (int j = 0; j < NCH; ++j) s += Psrc[(size_t)j * NODES + v];
    float fs = (float)max(s, 1);
    dn_out[v] = rsqrtf(fs);
    sdeg[v] = sqrtf(fs);
    int run = 0;
    #pragma unroll 8
    for (int j = 0; j < NCH; ++j) {
        int t = Pdst[(size_t)j * NODES + v];
        Pdst[(size_t)j * NODES + v] = (unsigned short)run;
        run += t;
    }
    cnt_in[v] = run;
    dn_in[v] = rsqrtf((float)max(run, 1));
}

// ---------------- row_ptr scan over cnt_in (2-dispatch, 49 blocks) ----------------
__global__ __launch_bounds__(SCAN_B) void scan_p1_kernel(const int* __restrict__ cnt,
                                                         int* __restrict__ row_ptr,
                                                         int* __restrict__ blk_sums) {
    __shared__ int sm[SCAN_B];
    int t = threadIdx.x;
    int idx = blockIdx.x * SCAN_B + t;
    int v = (idx < NODES) ? cnt[idx] : 0;
    sm[t] = v;
    __syncthreads();
    #pragma unroll
    for (int off = 1; off < SCAN_B; off <<= 1) {
        int u = (t >= off) ? sm[t - off] : 0;
        __syncthreads();
        sm[t] += u;
        __syncthreads();
    }
    if (idx < NODES) row_ptr[idx] = sm[t] - v;
    if (t == SCAN_B - 1) blk_sums[blockIdx.x] = sm[t];
}

__global__ __launch_bounds__(SCAN_B) void scan_p3_kernel(int* __restrict__ row_ptr,
                                                         const int* __restrict__ blk_sums) {
    __shared__ int soff;
    int t = threadIdx.x;
    if (t < 64) {
        int v = (t < blockIdx.x) ? blk_sums[t] : 0;
        #pragma unroll
        for (int off = 32; off > 0; off >>= 1) v += __shfl_xor(v, off);
        if (t == 0) soff = v;
    }
    __syncthreads();
    int idx = blockIdx.x * SCAN_B + t;
    if (idx < NODES) row_ptr[idx] += soff;
    if (idx == 0) row_ptr[NODES] = EDGES;
}

// ---------------- pass 3: CSR fill — pure streaming scatter (no LDS, no atomics) ----
__global__ __launch_bounds__(256) void fill_kernel(const int* __restrict__ src,
                                                   const int* __restrict__ dst,
                                                   const int* __restrict__ row_ptr,
                                                   const unsigned short* __restrict__ Pdst,
                                                   const unsigned short* __restrict__ rlocal,
                                                   int* __restrict__ csr_src) {
    int e = blockIdx.x * 256 + threadIdx.x;
    if (e >= EDGES) return;
    int d = dst[e];
    int chunk = e / CHE;
    int pos = row_ptr[d] + (int)Pdst[(size_t)chunk * NODES + d] + (int)rlocal[e];
    csr_src[pos] = src[e];
}

// ---------------- prescale to fp16 (quartered layout); tail: w2h + p2 zero ----------
__global__ __launch_bounds__(256) void prescale_w2h_kernel(const float* __restrict__ x,
                                                           const float* __restrict__ dn_out,
                                                           __half* __restrict__ hs,
                                                           const float* __restrict__ W1,
                                                           const float* __restrict__ W2,
                                                           __half* __restrict__ WhT1,
                                                           __half* __restrict__ WhT2,
                                                           float* __restrict__ p2a,
                                                           float* __restrict__ p2b) {
    int b = blockIdx.x;
    if (b >= PRE_NB) {
        // folded w2h: 128 tail blocks
        int b2 = b - PRE_NB;
        int idx = b2 * 256 + threadIdx.x;   // 0..32767
        if (b2 < 32) p2a[b2 * 256 + threadIdx.x] = 0.f;
        else if (b2 < 64) p2b[(b2 - 32) * 256 + threadIdx.x] = 0.f;
        const float* W = (idx < 16384) ? W1 : W2;
        __half* D = (idx < 16384) ? WhT1 : WhT2;
        int i = idx & 16383;
        int n = i >> 7;
        int k = i & 127;
        D[i] = __float2half(W[k * DIM + n]);    // D[n][k] = W[k][n]
        return;
    }
    int idx = b * 256 + threadIdx.x;   // over N*16
    int row = idx >> 4;
    int c8 = (idx & 15) * 8;
    float sc = dn_out[row];
    const float* xp = x + (size_t)row * DIM + c8;
    float4 v0 = *(const float4*)xp;
    float4 v1 = *(const float4*)(xp + 4);
    H8 u;
    u.h2[0] = __floats2half2_rn(v0.x * sc, v0.y * sc);
    u.h2[1] = __floats2half2_rn(v0.z * sc, v0.w * sc);
    u.h2[2] = __floats2half2_rn(v1.x * sc, v1.y * sc);
    u.h2[3] = __floats2half2_rn(v1.z * sc, v1.w * sc);
    int q = c8 >> 5;
    int off = c8 & 31;
    *(half8*)((char*)hs + ((size_t)(q * NODES + row) * 32 + off) * 2) = u.v;
}

// ---------------- pull: 1 wave per (node, quarter); 8 lanes x 8 B per edge ----------
__device__ __forceinline__ void acc_h4(half4 raw, float* a) {
    H4 u; u.v = raw;
    float2 f0 = __half22float2(u.h2[0]);
    float2 f1 = __half22float2(u.h2[1]);
    a[0] += f0.x; a[1] += f0.y; a[2] += f1.x; a[3] += f1.y;
}

__global__ __launch_bounds__(256) void pull_kernel(const __half* __restrict__ hs,
                                                   const int* __restrict__ row_ptr,
                                                   const int* __restrict__ csr_src,
                                                   const float* __restrict__ dn_in,
                                                   __half* __restrict__ agg) {
    int b = blockIdx.x;
    int q = (b & 7) >> 1;                    // quarter -> XCD pair {2q, 2q+1}
    int kq = ((b >> 3) << 1) + (b & 1);      // block index within quarter [0, 12500)
    int wid = threadIdx.x >> 6;
    int node = kq * 4 + wid;
    if (node >= NODES) return;
    int lane = threadIdx.x & 63;
    int s = lane >> 3;        // edge slot 0..7
    int c = lane & 7;         // 8-B chunk within 64-B quarter-row
    const char* base = (const char*)hs + (size_t)q * NODES * 64;
    int beg = row_ptr[node];
    int end = row_ptr[node + 1];
    float a[4];
    #pragma unroll
    for (int i = 0; i < 4; ++i) a[i] = 0.f;
    int eb = beg;
    for (; eb + 16 <= end; eb += 16) {
        int s0 = csr_src[eb + s];
        int s1 = csr_src[eb + 8 + s];
        half4 v0 = *(const half4*)(base + (size_t)s0 * 64 + c * 8);
        half4 v1 = *(const half4*)(base + (size_t)s1 * 64 + c * 8);
        acc_h4(v0, a);
        acc_h4(v1, a);
    }
    for (; eb + 8 <= end; eb += 8) {
        int s0 = csr_src[eb + s];
        half4 v0 = *(const half4*)(base + (size_t)s0 * 64 + c * 8);
        acc_h4(v0, a);
    }
    if (eb + s < end) {
        int s0 = csr_src[eb + s];
        half4 v0 = *(const half4*)(base + (size_t)s0 * 64 + c * 8);
        acc_h4(v0, a);
    }
    #pragma unroll
    for (int i = 0; i < 4; ++i) a[i] += __shfl_xor(a[i], 32);
    #pragma unroll
    for (int i = 0; i < 4; ++i) a[i] += __shfl_xor(a[i], 16);
    #pragma unroll
    for (int i = 0; i < 4; ++i) a[i] += __shfl_xor(a[i], 8);
    if (lane < 8) {
        float sc = dn_in[node];
        H4 u;
        u.h2[0] = __floats2half2_rn(a[0] * sc, a[1] * sc);
        u.h2[1] = __floats2half2_rn(a[2] * sc, a[3] * sc);
        *(half4*)((char*)agg + (size_t)node * 256 + q * 64 + c * 8) = u.v;
    }
}

// ---------------- MFMA GEMM (fp16 in/out) + p2-atomic stats epilogue ----------------
__global__ __launch_bounds__(256) void gemm_mfma_kernel(const __half* __restrict__ A,
                                                        const __half* __restrict__ WhT,
                                                        const float* __restrict__ bias,
                                                        __half* __restrict__ hraw,
                                                        float* __restrict__ p2) {
    __shared__ float smem[8704];
    __half* wl = (__half*)smem;

    int t = threadIdx.x;

    #pragma unroll
    for (int i = 0; i < 8; ++i) {
        int cch = t + 256 * i;
        int n = cch >> 4;
        int ch = cch & 15;
        *(float4*)((char*)wl + n * 272 + ch * 16) =
            *(const float4*)((const char*)WhT + n * 256 + ch * 16);
    }

    int w = t >> 6;
    int lane = t & 63;
    int m = lane & 15;
    int quad = lane >> 4;
    int r0 = blockIdx.x * 64 + w * 16;
    int arow = r0 + m;

    half8 afrag[4];
    if (arow < NODES) {
        const char* ap = (const char*)(A + (size_t)arow * DIM);
        #pragma unroll
        for (int kt = 0; kt < 4; ++kt)
            afrag[kt] = *(const half8*)(ap + kt * 64 + quad * 16);
    } else {
        #pragma unroll
        for (int kt = 0; kt < 4; ++kt)
            #pragma unroll
            for (int j = 0; j < 8; ++j)
                afrag[kt][j] = (_Float16)0.0f;
    }

    floatx4 acc[8];
    floatx4 zf = {0.f, 0.f, 0.f, 0.f};
    #pragma unroll
    for (int ct = 0; ct < 8; ++ct) acc[ct] = zf;

    __syncthreads();

    #pragma unroll
    for (int kt = 0; kt < 4; ++kt) {
        #pragma unroll
        for (int ct = 0; ct < 8; ++ct) {
            half8 b = *(const half8*)((const char*)wl + (ct * 16 + m) * 272 + kt * 64 + quad * 16);
            acc[ct] = __builtin_amdgcn_mfma_f32_16x16x32_f16(afrag[kt], b, acc[ct], 0, 0, 0);
        }
    }

    __syncthreads();   // wl fully consumed; reuse as stats scratch

    float* ps = smem;
    int g = w * 4 + quad;
    #pragma unroll
    for (int ct = 0; ct < 8; ++ct) {
        int col = ct * 16 + m;
        float bb = bias[col];
        float cs = 0.f, cq = 0.f;
        #pragma unroll
        for (int reg = 0; reg < 4; ++reg) {
            int row = r0 + quad * 4 + reg;
            if (row < NODES) {
                float o = acc[ct][reg] + bb;
                hraw[(size_t)row * DIM + col] = __float2half(o);
                cs += o;
                cq += o * o;
            }
        }
        ps[g * 128 + col] = cs;
        ps[2048 + g * 128 + col] = cq;
    }
    __syncthreads();

    float* pslot = p2 + (blockIdx.x & 31) * 256;
    if (t < 128) {
        float s = 0.f;
        #pragma unroll
        for (int gg = 0; gg < 16; ++gg) s += ps[gg * 128 + t];
        atomicAdd(pslot + t, s);
    } else {
        int cc = t - 128;
        float s = 0.f;
        #pragma unroll
        for (int gg = 0; gg < 16; ++gg) s += ps[2048 + gg * 128 + cc];
        atomicAdd(pslot + 128 + cc, s);
    }
}

// ---------------- BN apply + ReLU -> hs fp16 (scaled, QUARTERED); p2 prologue -------
__global__ __launch_bounds__(256) void bn_relu_scale_kernel(const __half* __restrict__ hraw,
                                                            __half* __restrict__ hs,
                                                            const float* __restrict__ p2,
                                                            const float* __restrict__ g,
                                                            const float* __restrict__ be,
                                                            const float* __restrict__ dn_out) {
    __shared__ float sm[256];
    {   // fold of stats_s2: coalesced 32x256 reduce, L2-hot
        float s = 0.f;
        #pragma unroll
        for (int r = 0; r < 32; ++r) s += p2[r * 256 + threadIdx.x];
        sm[threadIdx.x] = s;
    }
    __syncthreads();
    int idx = blockIdx.x * 256 + threadIdx.x;   // over N*16 (3125 blocks exact)
    if (idx >= NODES * 16) return;
    int row = idx >> 4;
    int c8 = (idx & 15) * 8;
    const float invN = 1.0f / NODES;
    H8 u;
    u.v = *(const half8*)((const char*)hraw + ((size_t)row * DIM + c8) * 2);
    float o[8];
    #pragma unroll
    for (int k = 0; k < 4; ++k) {
        float2 f = __half22float2(u.h2[k]);
        o[2 * k] = f.x;
        o[2 * k + 1] = f.y;
    }
    #pragma unroll
    for (int j = 0; j < 8; ++j) {
        int cj = c8 + j;
        float mu = sm[cj] * invN;
        float var = sm[128 + cj] * invN - mu * mu;
        float w = g[cj] * rsqrtf(var + EPS_BN);
        o[j] = fmaxf(w * (o[j] - mu) + be[cj], 0.f);
    }
    H8 us;
    float sc = dn_out[row];
    #pragma unroll
    for (int k = 0; k < 4; ++k)
        us.h2[k] = __floats2half2_rn(o[2 * k] * sc, o[2 * k + 1] * sc);
    int q = c8 >> 5;
    int off = c8 & 31;
    *(half8*)((char*)hs + ((size_t)(q * NODES + row) * 32 + off) * 2) = us.v;
}

// ---------------- BN + residual (quartered hs read) + ReLU -> out fp32 --------------
__global__ __launch_bounds__(256) void bn_res_relu_kernel(const __half* __restrict__ hraw,
                                                          const __half* __restrict__ hs,
                                                          const float* __restrict__ sdeg,
                                                          float* __restrict__ out,
                                                          const float* __restrict__ p2,
                                                          const float* __restrict__ g,
                                                          const float* __restrict__ be) {
    __shared__ float sm[256];
    {
        float s = 0.f;
        #pragma unroll
        for (int r = 0; r < 32; ++r) s += p2[r * 256 + threadIdx.x];
        sm[threadIdx.x] = s;
    }
    __syncthreads();
    int idx = blockIdx.x * 256 + threadIdx.x;   // over N*16
    if (idx >= NODES * 16) return;
    int row = idx >> 4;
    int c8 = (idx & 15) * 8;
    const float invN = 1.0f / NODES;
    float sd = sdeg[row];
    H8 u, ur;
    u.v = *(const half8*)((const char*)hraw + ((size_t)row * DIM + c8) * 2);
    int q = c8 >> 5;
    int off = c8 & 31;
    ur.v = *(const half8*)((const char*)hs + ((size_t)(q * NODES + row) * 32 + off) * 2);
    float o[8], r8[8];
    #pragma unroll
    for (int k = 0; k < 4; ++k) {
        float2 f = __half22float2(u.h2[k]);
        float2 fr = __half22float2(ur.h2[k]);
        o[2 * k] = f.x; o[2 * k + 1] = f.y;
        r8[2 * k] = fr.x * sd; r8[2 * k + 1] = fr.y * sd;
    }
    #pragma unroll
    for (int j = 0; j < 8; ++j) {
        int cj = c8 + j;
        float mu = sm[cj] * invN;
        float var = sm[128 + cj] * invN - mu * mu;
        float w = g[cj] * rsqrtf(var + EPS_BN);
        o[j] = fmaxf(w * (o[j] - mu) + be[cj] + r8[j], 0.f);
    }
    float* op = out + (size_t)row * DIM + c8;
    float4 o0 = {o[0], o[1], o[2], o[3]};
    float4 o1 = {o[4], o[5], o[6], o[7]};
    *(float4*)op = o0;
    *(float4*)(op + 4) = o1;
}

extern "C" void kernel_launch(void* const* d_in, const int* in_sizes, int n_in,
                              void* d_out, int out_size, void* d_ws, size_t ws_size,
                              hipStream_t stream) {
    const float* x      = (const float*)d_in[0];
    const int*   src    = (const int*)d_in[1];
    const int*   dst    = (const int*)d_in[2];
    const float* W1     = (const float*)d_in[3];
    const float* b1     = (const float*)d_in[4];
    const float* gamma1 = (const float*)d_in[5];
    const float* beta1  = (const float*)d_in[6];
    const float* W2     = (const float*)d_in[7];
    const float* b2     = (const float*)d_in[8];
    const float* gamma2 = (const float*)d_in[9];
    const float* beta2  = (const float*)d_in[10];
    float* out = (float*)d_out;

    char* wsc = (char*)d_ws;
    int*   cnt_in   = (int*)wsc;                     wsc += NODES * 4;
    float* dn_out   = (float*)wsc;                   wsc += NODES * 4;
    float* sdeg     = (float*)wsc;                   wsc += NODES * 4;
    float* dn_in    = (float*)wsc;                   wsc += NODES * 4;
    int*   row_ptr  = (int*)wsc;                     wsc += (NODES + 1) * 4;
    int*   csr_src  = (int*)wsc;                     wsc += EDGES * 4;
    int*   blk_sums = (int*)wsc;                     wsc += 64 * 4;
    __half* WhT1    = (__half*)wsc;                  wsc += DIM * DIM * 2;
    __half* WhT2    = (__half*)wsc;                  wsc += DIM * DIM * 2;
    float* p2a      = (float*)wsc;                   wsc += 32 * 256 * 4;
    float* p2b      = (float*)wsc;                   wsc += 32 * 256 * 4;
    unsigned short* Psrc = (unsigned short*)wsc;     wsc += (size_t)NCH * NODES * 2;
    unsigned short* Pdst = (unsigned short*)wsc;     wsc += (size_t)NCH * NODES * 2;
    unsigned short* rlocal = (unsigned short*)wsc;   wsc += (size_t)EDGES * 2;
    __half* hs      = (__half*)wsc;                  wsc += (size_t)NODES * DIM * 2;
    __half* agg     = (__half*)wsc;                  wsc += (size_t)NODES * DIM * 2;
    __half* hraw    = (__half*)wsc;                  wsc += (size_t)NODES * DIM * 2;

    const int T = 256;
    const int grid_e16  = (NODES * 16 + T - 1) / T;

    // graph prep — LDS-histogram pipeline; fill is a pure streaming scatter
    hist_part_kernel<<<dim3(NR * NCH, 2), T, 0, stream>>>(src, dst, Psrc, Pdst, rlocal);
    combine_kernel<<<(NODES + T - 1) / T, T, 0, stream>>>(Psrc, Pdst, cnt_in, dn_out, sdeg, dn_in);
    scan_p1_kernel<<<SCAN_NB, SCAN_B, 0, stream>>>(cnt_in, row_ptr, blk_sums);
    scan_p3_kernel<<<SCAN_NB, SCAN_B, 0, stream>>>(row_ptr, blk_sums);
    fill_kernel<<<EDGE_NB, T, 0, stream>>>(src, dst, row_ptr, Pdst, rlocal, csr_src);

    // prescale (quartered hs) + folded w2h + p2a/p2b zero
    prescale_w2h_kernel<<<PRE_NB + 128, T, 0, stream>>>(x, dn_out, hs, W1, W2, WhT1, WhT2, p2a, p2b);

    // layer 1: XCD-partitioned quartered pull, gemm -> p2a, BN (+fold)
    pull_kernel<<<PULL_NB, T, 0, stream>>>(hs, row_ptr, csr_src, dn_in, agg);
    gemm_mfma_kernel<<<GEMM_NB, T, 0, stream>>>(agg, WhT1, b1, hraw, p2a);
    bn_relu_scale_kernel<<<grid_e16, T, 0, stream>>>(hraw, hs, p2a, gamma1, beta1, dn_out);

    // layer 2
    pull_kernel<<<PULL_NB, T, 0, stream>>>(hs, row_ptr, csr_src, dn_in, agg);
    gemm_mfma_kernel<<<GEMM_NB, T, 0, stream>>>(agg, WhT2, b2, hraw, p2b);
    bn_res_relu_kernel<<<grid_e16, T, 0, stream>>>(hraw, hs, sdeg, out, p2b, gamma2, beta2);
}

// Round 11
// 264.041 us; speedup vs baseline: 1.2155x; 1.2155x over previous
//
#include <hip/hip_runtime.h>
#include <hip/hip_fp16.h>

#define NODES 50000
#define EDGES 800000
#define DIM 128
#define EPS_BN 1e-5f
#define SCAN_B 1024
#define SCAN_NB ((NODES + SCAN_B - 1) / SCAN_B)   // 49
#define GEMM_NB ((NODES + 63) / 64)               // 782
#define NCH 64                                    // edge chunks
#define CHE (EDGES / NCH)                         // 12500 edges/chunk
#define NR 4                                      // node ranges
#define RNG (NODES / NR)                          // 12500 nodes/range
#define PRE_NB ((NODES * 16) / 256)               // 3125 prescale blocks
#define EDGE_NB ((EDGES + 255) / 256)             // 3125 edge-parallel blocks

typedef _Float16 half8 __attribute__((ext_vector_type(8)));
typedef float floatx4 __attribute__((ext_vector_type(4)));

union H8 { half8 v; __half2 h2[4]; };

// ---------------- pass 1: partial LDS histograms; dst pass also emits local rank ----
__global__ __launch_bounds__(256) void hist_part_kernel(const int* __restrict__ src,
                                                        const int* __restrict__ dst,
                                                        unsigned short* __restrict__ Psrc,
                                                        unsigned short* __restrict__ Pdst,
                                                        unsigned short* __restrict__ rlocal) {
    __shared__ int h[RNG];   // 50 KB
    int chunk = blockIdx.x & (NCH - 1);
    int range = blockIdx.x >> 6;
    const int* arr = blockIdx.y ? dst : src;
    unsigned short* P = blockIdx.y ? Pdst : Psrc;
    int base = range * RNG;
    for (int i = threadIdx.x; i < RNG; i += 256) h[i] = 0;
    __syncthreads();
    int e0 = chunk * CHE;
    for (int e = e0 + threadIdx.x; e < e0 + CHE; e += 256) {
        unsigned r = (unsigned)(arr[e] - base);
        if (r < (unsigned)RNG) {
            int local = atomicAdd(&h[r], 1);
            if (blockIdx.y) rlocal[e] = (unsigned short)local;   // rank within (chunk, d)
        }
    }
    __syncthreads();
    for (int i = threadIdx.x; i < RNG; i += 256)
        P[(size_t)chunk * NODES + base + i] = (unsigned short)h[i];
}

// ---------------- pass 2: degrees + per-chunk scan bases ----------------
__global__ __launch_bounds__(256) void combine_kernel(const unsigned short* __restrict__ Psrc,
                                                      unsigned short* __restrict__ Pdst,
                                                      int* __restrict__ cnt_in,
                                                      float* __restrict__ dn_out,
                                                      float* __restrict__ sdeg,
                                                      float* __restrict__ dn_in) {
    int v = blockIdx.x * 256 + threadIdx.x;
    if (v >= NODES) return;
    int s = 0;
    #pragma unroll 8
    for (int j = 0; j < NCH; ++j) s += Psrc[(size_t)j * NODES + v];
    float fs = (float)max(s, 1);
    dn_out[v] = rsqrtf(fs);
    sdeg[v] = sqrtf(fs);
    int run = 0;
    #pragma unroll 8
    for (int j = 0; j < NCH; ++j) {
        int t = Pdst[(size_t)j * NODES + v];
        Pdst[(size_t)j * NODES + v] = (unsigned short)run;
        run += t;
    }
    cnt_in[v] = run;
    dn_in[v] = rsqrtf((float)max(run, 1));
}

// ---------------- row_ptr scan over cnt_in (2-dispatch, 49 blocks) ----------------
__global__ __launch_bounds__(SCAN_B) void scan_p1_kernel(const int* __restrict__ cnt,
                                                         int* __restrict__ row_ptr,
                                                         int* __restrict__ blk_sums) {
    __shared__ int sm[SCAN_B];
    int t = threadIdx.x;
    int idx = blockIdx.x * SCAN_B + t;
    int v = (idx < NODES) ? cnt[idx] : 0;
    sm[t] = v;
    __syncthreads();
    #pragma unroll
    for (int off = 1; off < SCAN_B; off <<= 1) {
        int u = (t >= off) ? sm[t - off] : 0;
        __syncthreads();
        sm[t] += u;
        __syncthreads();
    }
    if (idx < NODES) row_ptr[idx] = sm[t] - v;
    if (t == SCAN_B - 1) blk_sums[blockIdx.x] = sm[t];
}

__global__ __launch_bounds__(SCAN_B) void scan_p3_kernel(int* __restrict__ row_ptr,
                                                         const int* __restrict__ blk_sums) {
    __shared__ int soff;
    int t = threadIdx.x;
    if (t < 64) {
        int v = (t < blockIdx.x) ? blk_sums[t] : 0;
        #pragma unroll
        for (int off = 32; off > 0; off >>= 1) v += __shfl_xor(v, off);
        if (t == 0) soff = v;
    }
    __syncthreads();
    int idx = blockIdx.x * SCAN_B + t;
    if (idx < NODES) row_ptr[idx] += soff;
    if (idx == 0) row_ptr[NODES] = EDGES;
}

// ---------------- pass 3: CSR fill — pure streaming scatter (no LDS, no atomics) ----
// Slot = row_ptr[d] + per-chunk base (combine) + in-chunk rank (hist). Unique by
// construction; identical slot assignment to the old re-histogram version.
__global__ __launch_bounds__(256) void fill_kernel(const int* __restrict__ src,
                                                   const int* __restrict__ dst,
                                                   const int* __restrict__ row_ptr,
                                                   const unsigned short* __restrict__ Pdst,
                                                   const unsigned short* __restrict__ rlocal,
                                                   int* __restrict__ csr_src) {
    int e = blockIdx.x * 256 + threadIdx.x;
    if (e >= EDGES) return;
    int d = dst[e];
    int chunk = e / CHE;
    int pos = row_ptr[d] + (int)Pdst[(size_t)chunk * NODES + d] + (int)rlocal[e];
    csr_src[pos] = src[e];
}

// ---------------- prescale to fp16; tail blocks do W->fp16^T + p2a/p2b zero ---------
__global__ __launch_bounds__(256) void prescale_w2h_kernel(const float* __restrict__ x,
                                                           const float* __restrict__ dn_out,
                                                           __half* __restrict__ hs,
                                                           const float* __restrict__ W1,
                                                           const float* __restrict__ W2,
                                                           __half* __restrict__ WhT1,
                                                           __half* __restrict__ WhT2,
                                                           float* __restrict__ p2a,
                                                           float* __restrict__ p2b) {
    int b = blockIdx.x;
    if (b >= PRE_NB) {
        // folded w2h: 128 tail blocks
        int b2 = b - PRE_NB;
        int idx = b2 * 256 + threadIdx.x;   // 0..32767
        if (b2 < 32) p2a[b2 * 256 + threadIdx.x] = 0.f;
        else if (b2 < 64) p2b[(b2 - 32) * 256 + threadIdx.x] = 0.f;
        const float* W = (idx < 16384) ? W1 : W2;
        __half* D = (idx < 16384) ? WhT1 : WhT2;
        int i = idx & 16383;
        int n = i >> 7;
        int k = i & 127;
        D[i] = __float2half(W[k * DIM + n]);    // D[n][k] = W[k][n]
        return;
    }
    int idx = b * 256 + threadIdx.x;   // over N*16
    int row = idx >> 4;
    int c8 = (idx & 15) * 8;
    float sc = dn_out[row];
    const float* xp = x + (size_t)row * DIM + c8;
    float4 v0 = *(const float4*)xp;
    float4 v1 = *(const float4*)(xp + 4);
    H8 u;
    u.h2[0] = __floats2half2_rn(v0.x * sc, v0.y * sc);
    u.h2[1] = __floats2half2_rn(v0.z * sc, v0.w * sc);
    u.h2[2] = __floats2half2_rn(v1.x * sc, v1.y * sc);
    u.h2[3] = __floats2half2_rn(v1.z * sc, v1.w * sc);
    *(half8*)((char*)hs + ((size_t)row * DIM + c8) * 2) = u.v;
}

// ---------------- pull: 1 wave/node, 16 lanes x 16 B per edge, 4 edge slots ---------
__device__ __forceinline__ void acc_h8(half8 raw, float* a) {
    H8 u; u.v = raw;
    #pragma unroll
    for (int k = 0; k < 4; ++k) {
        float2 f = __half22float2(u.h2[k]);
        a[2 * k] += f.x;
        a[2 * k + 1] += f.y;
    }
}

__global__ __launch_bounds__(256) void pull_kernel(const __half* __restrict__ hs,
                                                   const int* __restrict__ row_ptr,
                                                   const int* __restrict__ csr_src,
                                                   const float* __restrict__ dn_in,
                                                   __half* __restrict__ agg) {
    int wid = threadIdx.x >> 6;
    int node = blockIdx.x * 4 + wid;
    if (node >= NODES) return;
    int lane = threadIdx.x & 63;
    int q = lane >> 4;        // edge slot 0..3
    int c = lane & 15;        // 16-B chunk within row
    const char* base = (const char*)hs;
    int beg = row_ptr[node];
    int end = row_ptr[node + 1];
    float a[8];
    #pragma unroll
    for (int i = 0; i < 8; ++i) a[i] = 0.f;
    int eb = beg;
    for (; eb + 16 <= end; eb += 16) {
        int s0 = csr_src[eb + q];
        int s1 = csr_src[eb + 4 + q];
        int s2 = csr_src[eb + 8 + q];
        int s3 = csr_src[eb + 12 + q];
        half8 v0 = *(const half8*)(base + (size_t)s0 * 256 + c * 16);
        half8 v1 = *(const half8*)(base + (size_t)s1 * 256 + c * 16);
        half8 v2 = *(const half8*)(base + (size_t)s2 * 256 + c * 16);
        half8 v3 = *(const half8*)(base + (size_t)s3 * 256 + c * 16);
        acc_h8(v0, a);
        acc_h8(v1, a);
        acc_h8(v2, a);
        acc_h8(v3, a);
    }
    for (; eb + 8 <= end; eb += 8) {
        int s0 = csr_src[eb + q];
        int s1 = csr_src[eb + 4 + q];
        half8 v0 = *(const half8*)(base + (size_t)s0 * 256 + c * 16);
        half8 v1 = *(const half8*)(base + (size_t)s1 * 256 + c * 16);
        acc_h8(v0, a);
        acc_h8(v1, a);
    }
    for (; eb + 4 <= end; eb += 4) {
        int s0 = csr_src[eb + q];
        half8 v0 = *(const half8*)(base + (size_t)s0 * 256 + c * 16);
        acc_h8(v0, a);
    }
    if (eb + q < end) {
        int s0 = csr_src[eb + q];
        half8 v0 = *(const half8*)(base + (size_t)s0 * 256 + c * 16);
        acc_h8(v0, a);
    }
    #pragma unroll
    for (int i = 0; i < 8; ++i) a[i] += __shfl_xor(a[i], 32);
    #pragma unroll
    for (int i = 0; i < 8; ++i) a[i] += __shfl_xor(a[i], 16);
    if (lane < 16) {
        float sc = dn_in[node];
        H8 u;
        #pragma unroll
        for (int k = 0; k < 4; ++k)
            u.h2[k] = __floats2half2_rn(a[2 * k] * sc, a[2 * k + 1] * sc);
        *(half8*)((char*)agg + (size_t)node * 256 + c * 16) = u.v;
    }
}

// ---------------- MFMA GEMM (fp16 in/out) + p2-atomic stats epilogue ----------------
__global__ __launch_bounds__(256) void gemm_mfma_kernel(const __half* __restrict__ A,
                                                        const __half* __restrict__ WhT,
                                                        const float* __restrict__ bias,
                                                        __half* __restrict__ hraw,
                                                        float* __restrict__ p2) {
    __shared__ float smem[8704];
    __half* wl = (__half*)smem;

    int t = threadIdx.x;

    #pragma unroll
    for (int i = 0; i < 8; ++i) {
        int cch = t + 256 * i;
        int n = cch >> 4;
        int ch = cch & 15;
        *(float4*)((char*)wl + n * 272 + ch * 16) =
            *(const float4*)((const char*)WhT + n * 256 + ch * 16);
    }

    int w = t >> 6;
    int lane = t & 63;
    int m = lane & 15;
    int quad = lane >> 4;
    int r0 = blockIdx.x * 64 + w * 16;
    int arow = r0 + m;

    half8 afrag[4];
    if (arow < NODES) {
        const char* ap = (const char*)(A + (size_t)arow * DIM);
        #pragma unroll
        for (int kt = 0; kt < 4; ++kt)
            afrag[kt] = *(const half8*)(ap + kt * 64 + quad * 16);
    } else {
        #pragma unroll
        for (int kt = 0; kt < 4; ++kt)
            #pragma unroll
            for (int j = 0; j < 8; ++j)
                afrag[kt][j] = (_Float16)0.0f;
    }

    floatx4 acc[8];
    floatx4 zf = {0.f, 0.f, 0.f, 0.f};
    #pragma unroll
    for (int ct = 0; ct < 8; ++ct) acc[ct] = zf;

    __syncthreads();

    #pragma unroll
    for (int kt = 0; kt < 4; ++kt) {
        #pragma unroll
        for (int ct = 0; ct < 8; ++ct) {
            half8 b = *(const half8*)((const char*)wl + (ct * 16 + m) * 272 + kt * 64 + quad * 16);
            acc[ct] = __builtin_amdgcn_mfma_f32_16x16x32_f16(afrag[kt], b, acc[ct], 0, 0, 0);
        }
    }

    __syncthreads();   // wl fully consumed; reuse as stats scratch

    float* ps = smem;
    int g = w * 4 + quad;
    #pragma unroll
    for (int ct = 0; ct < 8; ++ct) {
        int col = ct * 16 + m;
        float bb = bias[col];
        float cs = 0.f, cq = 0.f;
        #pragma unroll
        for (int reg = 0; reg < 4; ++reg) {
            int row = r0 + quad * 4 + reg;
            if (row < NODES) {
                float o = acc[ct][reg] + bb;
                hraw[(size_t)row * DIM + col] = __float2half(o);
                cs += o;
                cq += o * o;
            }
        }
        ps[g * 128 + col] = cs;
        ps[2048 + g * 128 + col] = cq;
    }
    __syncthreads();

    float* pslot = p2 + (blockIdx.x & 31) * 256;
    if (t < 128) {
        float s = 0.f;
        #pragma unroll
        for (int gg = 0; gg < 16; ++gg) s += ps[gg * 128 + t];
        atomicAdd(pslot + t, s);
    } else {
        int cc = t - 128;
        float s = 0.f;
        #pragma unroll
        for (int gg = 0; gg < 16; ++gg) s += ps[2048 + gg * 128 + cc];
        atomicAdd(pslot + 128 + cc, s);
    }
}

// ---------------- BN apply + ReLU (fp16 in) -> hs fp16 (scaled); p2-reduce prologue -
__global__ __launch_bounds__(256) void bn_relu_scale_kernel(const __half* __restrict__ hraw,
                                                            __half* __restrict__ hs,
                                                            const float* __restrict__ p2,
                                                            const float* __restrict__ g,
                                                            const float* __restrict__ be,
                                                            const float* __restrict__ dn_out) {
    __shared__ float sm[256];
    {   // fold of stats_s2: coalesced 32x256 reduce, L2-hot
        float s = 0.f;
        #pragma unroll
        for (int r = 0; r < 32; ++r) s += p2[r * 256 + threadIdx.x];
        sm[threadIdx.x] = s;
    }
    __syncthreads();
    int idx = blockIdx.x * 256 + threadIdx.x;   // over N*16 (3125 blocks exact)
    if (idx >= NODES * 16) return;
    int row = idx >> 4;
    int c8 = (idx & 15) * 8;
    const float invN = 1.0f / NODES;
    H8 u;
    u.v = *(const half8*)((const char*)hraw + ((size_t)row * DIM + c8) * 2);
    float o[8];
    #pragma unroll
    for (int k = 0; k < 4; ++k) {
        float2 f = __half22float2(u.h2[k]);
        o[2 * k] = f.x;
        o[2 * k + 1] = f.y;
    }
    #pragma unroll
    for (int j = 0; j < 8; ++j) {
        int cj = c8 + j;
        float mu = sm[cj] * invN;
        float var = sm[128 + cj] * invN - mu * mu;
        float w = g[cj] * rsqrtf(var + EPS_BN);
        o[j] = fmaxf(w * (o[j] - mu) + be[cj], 0.f);
    }
    H8 us;
    float sc = dn_out[row];
    #pragma unroll
    for (int k = 0; k < 4; ++k)
        us.h2[k] = __floats2half2_rn(o[2 * k] * sc, o[2 * k + 1] * sc);
    *(half8*)((char*)hs + ((size_t)row * DIM + c8) * 2) = us.v;
}

// ---------------- BN + residual + ReLU -> out fp32; p2-reduce prologue --------------
__global__ __launch_bounds__(256) void bn_res_relu_kernel(const __half* __restrict__ hraw,
                                                          const __half* __restrict__ hs,
                                                          const float* __restrict__ sdeg,
                                                          float* __restrict__ out,
                                                          const float* __restrict__ p2,
                                                          const float* __restrict__ g,
                                                          const float* __restrict__ be) {
    __shared__ float sm[256];
    {
        float s = 0.f;
        #pragma unroll
        for (int r = 0; r < 32; ++r) s += p2[r * 256 + threadIdx.x];
        sm[threadIdx.x] = s;
    }
    __syncthreads();
    int idx = blockIdx.x * 256 + threadIdx.x;   // over N*16
    if (idx >= NODES * 16) return;
    int row = idx >> 4;
    int c8 = (idx & 15) * 8;
    const float invN = 1.0f / NODES;
    float sd = sdeg[row];
    H8 u, ur;
    u.v = *(const half8*)((const char*)hraw + ((size_t)row * DIM + c8) * 2);
    ur.v = *(const half8*)((const char*)hs + ((size_t)row * DIM + c8) * 2);
    float o[8], r8[8];
    #pragma unroll
    for (int k = 0; k < 4; ++k) {
        float2 f = __half22float2(u.h2[k]);
        float2 fr = __half22float2(ur.h2[k]);
        o[2 * k] = f.x; o[2 * k + 1] = f.y;
        r8[2 * k] = fr.x * sd; r8[2 * k + 1] = fr.y * sd;
    }
    #pragma unroll
    for (int j = 0; j < 8; ++j) {
        int cj = c8 + j;
        float mu = sm[cj] * invN;
        float var = sm[128 + cj] * invN - mu * mu;
        float w = g[cj] * rsqrtf(var + EPS_BN);
        o[j] = fmaxf(w * (o[j] - mu) + be[cj] + r8[j], 0.f);
    }
    float* op = out + (size_t)row * DIM + c8;
    float4 o0 = {o[0], o[1], o[2], o[3]};
    float4 o1 = {o[4], o[5], o[6], o[7]};
    *(float4*)op = o0;
    *(float4*)(op + 4) = o1;
}

extern "C" void kernel_launch(void* const* d_in, const int* in_sizes, int n_in,
                              void* d_out, int out_size, void* d_ws, size_t ws_size,
                              hipStream_t stream) {
    const float* x      = (const float*)d_in[0];
    const int*   src    = (const int*)d_in[1];
    const int*   dst    = (const int*)d_in[2];
    const float* W1     = (const float*)d_in[3];
    const float* b1     = (const float*)d_in[4];
    const float* gamma1 = (const float*)d_in[5];
    const float* beta1  = (const float*)d_in[6];
    const float* W2     = (const float*)d_in[7];
    const float* b2     = (const float*)d_in[8];
    const float* gamma2 = (const float*)d_in[9];
    const float* beta2  = (const float*)d_in[10];
    float* out = (float*)d_out;

    char* wsc = (char*)d_ws;
    int*   cnt_in   = (int*)wsc;                     wsc += NODES * 4;
    float* dn_out   = (float*)wsc;                   wsc += NODES * 4;
    float* sdeg     = (float*)wsc;                   wsc += NODES * 4;
    float* dn_in    = (float*)wsc;                   wsc += NODES * 4;
    int*   row_ptr  = (int*)wsc;                     wsc += (NODES + 1) * 4;
    int*   csr_src  = (int*)wsc;                     wsc += EDGES * 4;
    int*   blk_sums = (int*)wsc;                     wsc += 64 * 4;
    __half* WhT1    = (__half*)wsc;                  wsc += DIM * DIM * 2;
    __half* WhT2    = (__half*)wsc;                  wsc += DIM * DIM * 2;
    float* p2a      = (float*)wsc;                   wsc += 32 * 256 * 4;
    float* p2b      = (float*)wsc;                   wsc += 32 * 256 * 4;
    unsigned short* Psrc = (unsigned short*)wsc;     wsc += (size_t)NCH * NODES * 2;
    unsigned short* Pdst = (unsigned short*)wsc;     wsc += (size_t)NCH * NODES * 2;
    unsigned short* rlocal = (unsigned short*)wsc;   wsc += (size_t)EDGES * 2;
    __half* hs      = (__half*)wsc;                  wsc += (size_t)NODES * DIM * 2;
    __half* agg     = (__half*)wsc;                  wsc += (size_t)NODES * DIM * 2;
    __half* hraw    = (__half*)wsc;                  wsc += (size_t)NODES * DIM * 2;

    const int T = 256;
    const int grid_pull = (NODES + 3) / 4;
    const int grid_e16  = (NODES * 16 + T - 1) / T;

    // graph prep — LDS-histogram pipeline; fill is a pure streaming scatter
    hist_part_kernel<<<dim3(NR * NCH, 2), T, 0, stream>>>(src, dst, Psrc, Pdst, rlocal);
    combine_kernel<<<(NODES + T - 1) / T, T, 0, stream>>>(Psrc, Pdst, cnt_in, dn_out, sdeg, dn_in);
    scan_p1_kernel<<<SCAN_NB, SCAN_B, 0, stream>>>(cnt_in, row_ptr, blk_sums);
    scan_p3_kernel<<<SCAN_NB, SCAN_B, 0, stream>>>(row_ptr, blk_sums);
    fill_kernel<<<EDGE_NB, T, 0, stream>>>(src, dst, row_ptr, Pdst, rlocal, csr_src);

    // prescale + folded w2h + p2a/p2b zero
    prescale_w2h_kernel<<<PRE_NB + 128, T, 0, stream>>>(x, dn_out, hs, W1, W2, WhT1, WhT2, p2a, p2b);

    // layer 1
    pull_kernel<<<grid_pull, T, 0, stream>>>(hs, row_ptr, csr_src, dn_in, agg);
    gemm_mfma_kernel<<<GEMM_NB, T, 0, stream>>>(agg, WhT1, b1, hraw, p2a);
    bn_relu_scale_kernel<<<grid_e16, T, 0, stream>>>(hraw, hs, p2a, gamma1, beta1, dn_out);

    // layer 2
    pull_kernel<<<grid_pull, T, 0, stream>>>(hs, row_ptr, csr_src, dn_in, agg);
    gemm_mfma_kernel<<<GEMM_NB, T, 0, stream>>>(agg, WhT2, b2, hraw, p2b);
    bn_res_relu_kernel<<<grid_e16, T, 0, stream>>>(hraw, hs, sdeg, out, p2b, gamma2, beta2);
}